// Round 3
// baseline (2437.406 us; speedup 1.0000x reference)
//
#include <hip/hip_runtime.h>
#include <hip/hip_bf16.h>
#include <math.h>

// mLSTM block, fp32 baseline, v2 (workspace slimmed to ~194MB).
//  B=2 L=4096 DIM=1024 H=16 DH=64 INNER=1024
//  Chunked-parallel scan (GLA-style) with T=64 chunk, factored gates in fp32.

#define BB 2
#define LL 4096
#define NH 16
#define DH 64
#define INNER_ 1024
#define TT 64            // chunk length
#define NCC 64           // chunks per sequence = L/T
#define NINST 2048       // BB*NH*NCC
#define MTOK 8192        // B*L

// ---------------------------------------------------------------------------
// Generic fp32 GEMM: C[m][n] = act(sum_k A[m][k]*B[n][k] + bias[n])
// Tiles: BM=BN=128, BK=16, 256 threads, 8x8 accum per thread.
// act: 0=none, 1=exp(x+bias), 2=sigmoid(x+bias)
// ---------------------------------------------------------------------------
#define GBM 128
#define GBN 128
#define GBK 16

__global__ __launch_bounds__(256) void gemm_nt(
    const float* __restrict__ A, int lda,
    const float* __restrict__ Bw, int ldb,
    float* __restrict__ C, int ldc,
    int K, const float* __restrict__ bias, int act)
{
    __shared__ float As[GBK][GBM];
    __shared__ float Bs[GBK][GBN];
    const int bm = blockIdx.x * GBM;
    const int bn = blockIdx.y * GBN;
    const int tid = threadIdx.x;
    const int tm = (tid >> 4) * 8;
    const int tn = (tid & 15) * 8;

    float acc[8][8];
#pragma unroll
    for (int i = 0; i < 8; i++)
#pragma unroll
        for (int j = 0; j < 8; j++) acc[i][j] = 0.f;

    for (int k0 = 0; k0 < K; k0 += GBK) {
        __syncthreads();
#pragma unroll
        for (int i = 0; i < 2; i++) {
            int id = tid + i * 256;          // 0..511
            int r = id >> 2;                  // 0..127
            int kq = (id & 3) * 4;
            float4 av = *(const float4*)(A + (size_t)(bm + r) * lda + k0 + kq);
            As[kq + 0][r] = av.x; As[kq + 1][r] = av.y;
            As[kq + 2][r] = av.z; As[kq + 3][r] = av.w;
            float4 bv = *(const float4*)(Bw + (size_t)(bn + r) * ldb + k0 + kq);
            Bs[kq + 0][r] = bv.x; Bs[kq + 1][r] = bv.y;
            Bs[kq + 2][r] = bv.z; Bs[kq + 3][r] = bv.w;
        }
        __syncthreads();
#pragma unroll
        for (int kk = 0; kk < GBK; kk++) {
            float4 a0 = *(const float4*)&As[kk][tm];
            float4 a1 = *(const float4*)&As[kk][tm + 4];
            float4 b0 = *(const float4*)&Bs[kk][tn];
            float4 b1 = *(const float4*)&Bs[kk][tn + 4];
            float ar[8] = {a0.x, a0.y, a0.z, a0.w, a1.x, a1.y, a1.z, a1.w};
            float br[8] = {b0.x, b0.y, b0.z, b0.w, b1.x, b1.y, b1.z, b1.w};
#pragma unroll
            for (int i = 0; i < 8; i++)
#pragma unroll
                for (int j = 0; j < 8; j++) acc[i][j] += ar[i] * br[j];
        }
    }

#pragma unroll
    for (int i = 0; i < 8; i++) {
        size_t row = (size_t)(bm + tm + i) * ldc + bn + tn;
#pragma unroll
        for (int j = 0; j < 8; j++) {
            float v = acc[i][j];
            if (act == 1) v = expf(v + bias[bn + tn + j]);
            else if (act == 2) {
                float z = v + bias[bn + tn + j];
                v = 1.0f / (1.0f + expf(-z));
            }
            C[row + j] = v;
        }
    }
}

// ---------------------------------------------------------------------------
// og[i] *= sigmoid(xg[i]) — elementwise 8M floats, float4.
// ---------------------------------------------------------------------------
__global__ __launch_bounds__(256) void gate_fuse(float* og, const float* __restrict__ xg)
{
    size_t i = ((size_t)blockIdx.x * 256 + threadIdx.x) * 4;
    float4 o = *(float4*)(og + i);
    float4 g = *(const float4*)(xg + i);
    o.x *= 1.0f / (1.0f + expf(-g.x));
    o.y *= 1.0f / (1.0f + expf(-g.y));
    o.z *= 1.0f / (1.0f + expf(-g.z));
    o.w *= 1.0f / (1.0f + expf(-g.w));
    *(float4*)(og + i) = o;
}

// ---------------------------------------------------------------------------
// Per-head RMSNorm, in place. One wave per 64-float row.
// ---------------------------------------------------------------------------
__global__ __launch_bounds__(256) void rmsnorm_heads(float* t, const float* __restrict__ w)
{
    int row = blockIdx.x * 4 + (threadIdx.x >> 6);
    int lane = threadIdx.x & 63;
    size_t idx = (size_t)row * 64 + lane;
    float x = t[idx];
    float ss = x * x;
#pragma unroll
    for (int o = 32; o; o >>= 1) ss += __shfl_xor(ss, o);
    float s = rsqrtf(ss * (1.0f / 64.0f) + 1e-6f);
    t[idx] = x * s * w[lane];
}

// ---------------------------------------------------------------------------
// Phase A1: per (inst, d) chain over the 64 tokens of the chunk.
//   F_t = prod_{u<=t} fg ;  q <- q*F_t ;  k <- ig*k/F_t ;  Fend = F_{T-1}
// ---------------------------------------------------------------------------
__global__ __launch_bounds__(256) void prep_kernel(
    float* q, float* k,
    const float* __restrict__ ig, const float* __restrict__ fg,
    float* __restrict__ Fend)
{
    int gid = blockIdx.x * 256 + threadIdx.x;   // [0, NINST*64)
    int d = gid & 63;
    int inst = gid >> 6;
    int c = inst & (NCC - 1);
    int bh = inst >> 6;
    int b = bh >> 4, h = bh & 15;
    size_t idx = ((size_t)(b * LL + c * TT)) * INNER_ + h * DH + d;
    float F = 1.0f;
    for (int t = 0; t < TT; t++, idx += INNER_) {
        F *= fg[idx];
        q[idx] = q[idx] * F;
        k[idx] = ig[idx] * k[idx] / F;
    }
    Fend[gid] = F;
}

// ---------------------------------------------------------------------------
// Phase A2: per chunk-instance: G[d][e] = sum_s k~[s][d]*v[s][e]; gsum[d]=sum_s k~[s][d]
// ---------------------------------------------------------------------------
__global__ __launch_bounds__(256) void chunk_sum_kernel(
    const float* __restrict__ kt, const float* __restrict__ v,
    float* __restrict__ G, float* __restrict__ gsum)
{
    __shared__ float ks[TT][68];
    __shared__ float vs[TT][68];
    int inst = blockIdx.x;
    int c = inst & (NCC - 1);
    int bh = inst >> 6;
    int b = bh >> 4, h = bh & 15;
    int tid = threadIdx.x;
    size_t base = ((size_t)(b * LL + c * TT)) * INNER_ + h * DH;
#pragma unroll
    for (int i = 0; i < 4; i++) {
        int id = tid + i * 256;
        int s = id >> 4, dq = (id & 15) * 4;
        *(float4*)&ks[s][dq] = *(const float4*)(kt + base + (size_t)s * INNER_ + dq);
        *(float4*)&vs[s][dq] = *(const float4*)(v + base + (size_t)s * INNER_ + dq);
    }
    __syncthreads();
    int d = tid >> 2;
    int e0 = (tid & 3) * 16;
    float acc[16];
#pragma unroll
    for (int j = 0; j < 16; j++) acc[j] = 0.f;
    float gs = 0.f;
    for (int s = 0; s < TT; s++) {
        float kv = ks[s][d];
        gs += kv;
        const float4* vr = (const float4*)&vs[s][e0];
        float4 v0 = vr[0], v1 = vr[1], v2 = vr[2], v3 = vr[3];
        acc[0] += kv * v0.x; acc[1] += kv * v0.y; acc[2] += kv * v0.z; acc[3] += kv * v0.w;
        acc[4] += kv * v1.x; acc[5] += kv * v1.y; acc[6] += kv * v1.z; acc[7] += kv * v1.w;
        acc[8] += kv * v2.x; acc[9] += kv * v2.y; acc[10] += kv * v2.z; acc[11] += kv * v2.w;
        acc[12] += kv * v3.x; acc[13] += kv * v3.y; acc[14] += kv * v3.z; acc[15] += kv * v3.w;
    }
    float* Gp = G + (size_t)inst * 4096 + (size_t)d * 64 + e0;
#pragma unroll
    for (int j4 = 0; j4 < 4; j4++) {
        float4 o; o.x = acc[j4 * 4]; o.y = acc[j4 * 4 + 1]; o.z = acc[j4 * 4 + 2]; o.w = acc[j4 * 4 + 3];
        *(float4*)&Gp[j4 * 4] = o;
    }
    if ((tid & 3) == 0) gsum[(size_t)inst * 64 + d] = gs;
}

// ---------------------------------------------------------------------------
// Phase B: sequential over chunks, parallel over (bh, state element).
// ---------------------------------------------------------------------------
__global__ __launch_bounds__(256) void state_kernel(
    const float* __restrict__ G, const float* __restrict__ gsum,
    const float* __restrict__ Fend,
    float* __restrict__ C0, float* __restrict__ n0)
{
    int bh = blockIdx.x >> 4;
    int part = blockIdx.x & 15;
    int p = part * 256 + threadIdx.x;  // [0,4096)
    int d = p >> 6;
    float C = 0.f, n = 0.f;
    for (int c = 0; c < NCC; c++) {
        size_t inst = (size_t)bh * NCC + c;
        C0[inst * 4096 + p] = C;
        float f = Fend[inst * 64 + d];
        C = f * (C + G[inst * 4096 + p]);
        if (p < 64) {
            n0[inst * 64 + p] = n;
            n = Fend[inst * 64 + p] * (n + gsum[inst * 64 + p]);
        }
    }
}

// ---------------------------------------------------------------------------
// Phase C: per chunk-instance output:
//   A = tril(q~ k~^T); den_t = max(q~_t.n0 + rowsum(A_t), 1)
//   num = q~ @ C0 + A @ V ; g = num/den * og'   (og' already includes sigmoid(x_gate))
// ---------------------------------------------------------------------------
__global__ __launch_bounds__(256) void scan_out_kernel(
    const float* qt /*aliases g*/, const float* __restrict__ kt,
    const float* __restrict__ v, const float* __restrict__ og,
    const float* __restrict__ C0, const float* __restrict__ n0,
    float* g /*aliases qt*/)
{
    __shared__ float Qs[TT][68];
    __shared__ float Ks[TT][68];
    __shared__ float As[TT][68];
    __shared__ float den[TT];
    int inst = blockIdx.x;
    int c = inst & (NCC - 1);
    int bh = inst >> 6;
    int b = bh >> 4, h = bh & 15;
    int tid = threadIdx.x;
    size_t base = ((size_t)(b * LL + c * TT)) * INNER_ + h * DH;

    // stage q~, k~
#pragma unroll
    for (int i = 0; i < 4; i++) {
        int id = tid + i * 256;
        int s = id >> 4, dq = (id & 15) * 4;
        *(float4*)&Qs[s][dq] = *(const float4*)(qt + base + (size_t)s * INNER_ + dq);
        *(float4*)&Ks[s][dq] = *(const float4*)(kt + base + (size_t)s * INNER_ + dq);
    }
    __syncthreads();

    const int trow = tid >> 2;       // t row this thread owns
    const int s0 = tid & 3;          // A columns s = s0 + 4j (interleaved)
    {
        float a[16];
#pragma unroll
        for (int j = 0; j < 16; j++) a[j] = 0.f;
        for (int d4 = 0; d4 < 16; d4++) {
            float4 qv = *(const float4*)&Qs[trow][d4 * 4];
#pragma unroll
            for (int j = 0; j < 16; j++) {
                float4 kv = *(const float4*)&Ks[s0 + 4 * j][d4 * 4];
                a[j] += qv.x * kv.x + qv.y * kv.y + qv.z * kv.z + qv.w * kv.w;
            }
        }
#pragma unroll
        for (int j = 0; j < 16; j++) {
            int s = s0 + 4 * j;
            As[trow][s] = (s <= trow) ? a[j] : 0.f;
        }
    }
    __syncthreads();

    // load C0 into Ks (k~ no longer needed); one wave computes den
#pragma unroll
    for (int i = 0; i < 4; i++) {
        int id = tid + i * 256;
        int d = id >> 4, eq = (id & 15) * 4;
        *(float4*)&Ks[d][eq] = *(const float4*)(C0 + (size_t)inst * 4096 + (size_t)d * 64 + eq);
    }
    if (tid < TT) {
        float s = 0.f;
#pragma unroll 8
        for (int j = 0; j < TT; j++) s += As[tid][j];
        const float* n0p = n0 + (size_t)inst * 64;
        float dn = 0.f;
#pragma unroll 8
        for (int d = 0; d < DH; d++) dn += Qs[tid][d] * n0p[d];
        den[tid] = fmaxf(s + dn, 1.0f);
    }
    __syncthreads();

    const int e0 = (tid & 3) * 16;
    float num[16];
#pragma unroll
    for (int j = 0; j < 16; j++) num[j] = 0.f;

    // num += q~ @ C0
    for (int d = 0; d < DH; d++) {
        float qd = Qs[trow][d];
        const float4* kr = (const float4*)&Ks[d][e0];
        float4 k0 = kr[0], k1 = kr[1], k2 = kr[2], k3 = kr[3];
        num[0] += qd * k0.x; num[1] += qd * k0.y; num[2] += qd * k0.z; num[3] += qd * k0.w;
        num[4] += qd * k1.x; num[5] += qd * k1.y; num[6] += qd * k1.z; num[7] += qd * k1.w;
        num[8] += qd * k2.x; num[9] += qd * k2.y; num[10] += qd * k2.z; num[11] += qd * k2.w;
        num[12] += qd * k3.x; num[13] += qd * k3.y; num[14] += qd * k3.z; num[15] += qd * k3.w;
    }
    __syncthreads();

    // load v into Qs (q~ no longer needed)
#pragma unroll
    for (int i = 0; i < 4; i++) {
        int id = tid + i * 256;
        int s = id >> 4, dq = (id & 15) * 4;
        *(float4*)&Qs[s][dq] = *(const float4*)(v + base + (size_t)s * INNER_ + dq);
    }
    __syncthreads();

    // num += A @ V
    for (int s = 0; s < TT; s++) {
        float av = As[trow][s];
        const float4* vr = (const float4*)&Qs[s][e0];
        float4 v0 = vr[0], v1 = vr[1], v2 = vr[2], v3 = vr[3];
        num[0] += av * v0.x; num[1] += av * v0.y; num[2] += av * v0.z; num[3] += av * v0.w;
        num[4] += av * v1.x; num[5] += av * v1.y; num[6] += av * v1.z; num[7] += av * v1.w;
        num[8] += av * v2.x; num[9] += av * v2.y; num[10] += av * v2.z; num[11] += av * v2.w;
        num[12] += av * v3.x; num[13] += av * v3.y; num[14] += av * v3.z; num[15] += av * v3.w;
    }

    float inv = 1.0f / den[trow];
    size_t orow = base + (size_t)trow * INNER_ + e0;
#pragma unroll
    for (int j = 0; j < 16; j++) {
        g[orow + j] = num[j] * inv * og[orow + j];
    }
}

// diagnostic: encode ws_size (MB) into out[0] if workspace is too small
__global__ void ws_sentinel(float* out, float v) { out[0] = v; }

// ---------------------------------------------------------------------------
extern "C" void kernel_launch(void* const* d_in, const int* in_sizes, int n_in,
                              void* d_out, int out_size, void* d_ws, size_t ws_size,
                              hipStream_t stream)
{
    const float* x          = (const float*)d_in[0];
    const float* in_proj_w  = (const float*)d_in[1];
    const float* q_proj_w   = (const float*)d_in[2];
    const float* k_proj_w   = (const float*)d_in[3];
    const float* v_proj_w   = (const float*)d_in[4];
    const float* i_gate_w   = (const float*)d_in[5];
    const float* i_gate_b   = (const float*)d_in[6];
    const float* f_gate_w   = (const float*)d_in[7];
    const float* f_gate_b   = (const float*)d_in[8];
    const float* o_gate_w   = (const float*)d_in[9];
    const float* o_gate_b   = (const float*)d_in[10];
    const float* q_norm_w   = (const float*)d_in[11];
    const float* k_norm_w   = (const float*)d_in[12];
    const float* out_proj_w = (const float*)d_in[13];
    float* out = (float*)d_out;

    // workspace: 6 slots of 32MB + 1.5MB smalls = ~194MB
    const size_t SLOT = (size_t)32 << 20;
    const size_t NEED = 6 * SLOT + 3 * (size_t)NINST * 64 * 4;
    if (ws_size < NEED) {
        ws_sentinel<<<1, 1, 0, stream>>>(out, 1000.0f + (float)(ws_size >> 20));
        return;
    }
    char* ws = (char*)d_ws;
    float* xi  = (float*)(ws + 0 * SLOT);   // x_inner
    float* xg  = (float*)(ws + 1 * SLOT);   // x_gate, then v
    float* qb  = (float*)(ws + 2 * SLOT);   // q -> q~ -> g
    float* kb  = (float*)(ws + 3 * SLOT);   // k -> k~
    float* igb = (float*)(ws + 4 * SLOT);   // ig, then G
    float* fgb = (float*)(ws + 5 * SLOT);   // fg, then C0
    float* Fend = (float*)(ws + 6 * SLOT);
    float* gsum = Fend + (size_t)NINST * 64;
    float* n0   = gsum + (size_t)NINST * 64;
    float* vb = xg;        // v reuses x_gate slot
    float* ogb = out;      // og lives in d_out until the final GEMM
    float* G  = igb;
    float* C0 = fgb;

    dim3 blk(256);
    dim3 g_mn(MTOK / GBM, 1024 / GBN);

    // 1-2) x_inner / x_gate = x @ in_proj_w^T (split)
    gemm_nt<<<g_mn, blk, 0, stream>>>(x, 1024, in_proj_w, 1024, xi, 1024, 1024, nullptr, 0);
    gemm_nt<<<g_mn, blk, 0, stream>>>(x, 1024, in_proj_w + (size_t)1024 * 1024, 1024, xg, 1024, 1024, nullptr, 0);
    // 3) og = sigmoid(x_inner @ o_gate_w^T + b)  (into d_out)
    gemm_nt<<<g_mn, blk, 0, stream>>>(xi, 1024, o_gate_w, 1024, ogb, 1024, 1024, o_gate_b, 2);
    // 4) og *= sigmoid(x_gate); x_gate slot freed
    gate_fuse<<<MTOK * 1024 / (256 * 4), blk, 0, stream>>>(ogb, xg);
    // 5-7) q, k, v projections (v into the freed x_gate slot)
    gemm_nt<<<g_mn, blk, 0, stream>>>(xi, 1024, q_proj_w, 1024, qb, 1024, 1024, nullptr, 0);
    gemm_nt<<<g_mn, blk, 0, stream>>>(xi, 1024, k_proj_w, 1024, kb, 1024, 1024, nullptr, 0);
    gemm_nt<<<g_mn, blk, 0, stream>>>(xi, 1024, v_proj_w, 1024, vb, 1024, 1024, nullptr, 0);
    // 8-9) per-head RMSNorm on q,k (in place)
    rmsnorm_heads<<<MTOK * NH / 4, blk, 0, stream>>>(qb, q_norm_w);
    rmsnorm_heads<<<MTOK * NH / 4, blk, 0, stream>>>(kb, k_norm_w);
    // 10-11) gate projections
    gemm_nt<<<g_mn, blk, 0, stream>>>(xi, 1024, i_gate_w, 1024, igb, 1024, 1024, i_gate_b, 1);
    gemm_nt<<<g_mn, blk, 0, stream>>>(xi, 1024, f_gate_w, 1024, fgb, 1024, 1024, f_gate_b, 2);
    // 12) factor gates into q~,k~ (in place), record Fend
    prep_kernel<<<NINST * 64 / 256, blk, 0, stream>>>(qb, kb, igb, fgb, Fend);
    // 13) per-chunk G = k~^T V, gsum (G overwrites ig slot)
    chunk_sum_kernel<<<NINST, blk, 0, stream>>>(kb, vb, G, gsum);
    // 14) sequential inter-chunk state propagation (C0 overwrites fg slot)
    state_kernel<<<32 * 16, blk, 0, stream>>>(G, gsum, Fend, C0, n0);
    // 15) per-chunk outputs + gating; g overwrites q~
    scan_out_kernel<<<NINST, blk, 0, stream>>>(qb, kb, vb, ogb, C0, n0, qb);
    // 16) out = g @ out_proj_w^T  (overwrites og in d_out)
    gemm_nt<<<g_mn, blk, 0, stream>>>(qb, 1024, out_proj_w, 1024, out, 1024, 1024, nullptr, 0);
}

// Round 6
// 700.115 us; speedup vs baseline: 3.4814x; 3.4814x over previous
//
#include <hip/hip_runtime.h>
#include <math.h>

// mLSTM block v4: fp16 MFMA GEMMs (m97 structure) + fp32 chunked scan.
// v3 (bf16) failed absmax 0.148 vs 0.0925 -> pure rounding; fp16 is 8x finer
// at the same MFMA rate. All O(1)-magnitude operands; extreme magnitudes stay
// in the fp32 scan kernels (unchanged, validated at absmax 0.0156 in v2).
//  B=2 L=4096 DIM=1024 H=16 DH=64 INNER=1024, chunk T=64.
//  ws layout (<=179.5MB, ws>=194MB proven):
//   [0,16)   xh           -> later C0 (32MB spans [0,32))
//   [16,32)  xih
//   [32,48)  igp (fp16)   -> later G (32MB spans [32,64)) -> later gh (16MB)
//   [48,64)  fgp (fp16)
//   [64,96)  xg f32 -> v f32
//   [96,128) q f32
//   [128,160) k f32
//   [160,178) weights fp16
//   [178,179.5) Fend/gsum/n0

#define BB 2
#define LL 4096
#define NH 16
#define DH 64
#define INNER_ 1024
#define TT 64
#define NCC 64
#define NINST 2048
#define MTOK 8192

typedef __attribute__((ext_vector_type(8))) _Float16 f16x8;
typedef __attribute__((ext_vector_type(4))) _Float16 f16x4;
typedef __attribute__((ext_vector_type(4))) float f32x4;

// async global->LDS, 16B per lane; lds dest is wave-uniform base (HW adds lane*16)
__device__ __forceinline__ void gload_lds16(const void* g, void* l) {
    __builtin_amdgcn_global_load_lds(
        (const __attribute__((address_space(1))) unsigned int*)g,
        (__attribute__((address_space(3))) unsigned int*)l, 16, 0, 0);
}

// ---------------------------------------------------------------------------
// fp32 -> fp16 cast, 4 elems/thread
// ---------------------------------------------------------------------------
__global__ __launch_bounds__(256) void cast_f2h(
    const float* __restrict__ s, _Float16* __restrict__ d, int n4)
{
    int i = blockIdx.x * 256 + threadIdx.x;
    if (i >= n4) return;
    float4 a = ((const float4*)s)[i];
    f16x4 o;
    o.x = (_Float16)a.x; o.y = (_Float16)a.y;
    o.z = (_Float16)a.z; o.w = (_Float16)a.w;
    *(f16x4*)(d + (size_t)i * 4) = o;
}

// ---------------------------------------------------------------------------
// fp16 MFMA GEMM (nt): C[m][n] = act(sum_k A[m][k]*Bw[n][k] + bias[n])
// A,Bw fp16 row-major; 128x128 tile, BK=64, 4 waves (each 64x64 out),
// global_load_lds staging, 16x16x32 f16 MFMA, fp32 accum.
// act: 0 none, 1 +bias, 2 sigmoid(x+bias).  f16out: write fp16 else fp32.
// grid: (N/128, M/128)
// ---------------------------------------------------------------------------
#define MBM 128
#define MBN 128
#define MBK 64

__global__ __launch_bounds__(256) void gemm_f16(
    const _Float16* __restrict__ A, int lda,
    const _Float16* __restrict__ Bw, int ldb,
    void* __restrict__ Cout, int ldc, int K,
    const float* __restrict__ bias, int act, int f16out)
{
    __shared__ _Float16 As[MBM][MBK];   // 16 KB
    __shared__ _Float16 Bs[MBN][MBK];   // 16 KB
    const int tid = threadIdx.x;
    const int wave = tid >> 6, lane = tid & 63;
    const int l15 = lane & 15, l4 = lane >> 4;
    const int bn = blockIdx.x * MBN;
    const int bm = blockIdx.y * MBM;
    const int wr = wave >> 1, wc = wave & 1;   // 2x2 wave grid, 64x64 each

    f32x4 acc[4][4] = {};

    const int nt = K / MBK;
    for (int t = 0; t < nt; ++t) {
        const int k0 = t * MBK;
        // stage A,B tiles: idx=i*256+tid; row=idx>>3, seg=idx&7;
        // LDS linear offset idx*16B = i*4096 + wave*1024 + lane*16.
#pragma unroll
        for (int i = 0; i < 4; ++i) {
            int idx = i * 256 + tid;
            int row = idx >> 3, seg = idx & 7;
            gload_lds16(A + (size_t)(bm + row) * lda + k0 + seg * 8,
                        (char*)&As[0][0] + i * 4096 + wave * 1024);
            gload_lds16(Bw + (size_t)(bn + row) * ldb + k0 + seg * 8,
                        (char*)&Bs[0][0] + i * 4096 + wave * 1024);
        }
        __syncthreads();
#pragma unroll
        for (int kk = 0; kk < MBK / 32; ++kk) {
            f16x8 a[4], b[4];
#pragma unroll
            for (int i = 0; i < 4; ++i)
                a[i] = *(const f16x8*)&As[wr * 64 + i * 16 + l15][kk * 32 + l4 * 8];
#pragma unroll
            for (int j = 0; j < 4; ++j)
                b[j] = *(const f16x8*)&Bs[wc * 64 + j * 16 + l15][kk * 32 + l4 * 8];
#pragma unroll
            for (int i = 0; i < 4; ++i)
#pragma unroll
                for (int j = 0; j < 4; ++j)
                    acc[i][j] = __builtin_amdgcn_mfma_f32_16x16x32_f16(
                        a[i], b[j], acc[i][j], 0, 0, 0);
        }
        __syncthreads();
    }

    // epilogue: D row=(lane>>4)*4+reg, col=lane&15 (m89-verified, dtype-indep)
    float* Cf = (float*)Cout;
    _Float16* Ch = (_Float16*)Cout;
#pragma unroll
    for (int i = 0; i < 4; ++i) {
#pragma unroll
        for (int r = 0; r < 4; ++r) {
            size_t m = (size_t)(bm + wr * 64 + i * 16 + l4 * 4 + r);
#pragma unroll
            for (int j = 0; j < 4; ++j) {
                int n = bn + wc * 64 + j * 16 + l15;
                float v = acc[i][j][r];
                if (act) {
                    v += bias[n];
                    if (act == 2) v = 1.0f / (1.0f + expf(-v));
                }
                if (f16out) Ch[m * ldc + n] = (_Float16)v;
                else        Cf[m * ldc + n] = v;
            }
        }
    }
}

// ---------------------------------------------------------------------------
// og[i] *= sigmoid(xg[i])
// ---------------------------------------------------------------------------
__global__ __launch_bounds__(256) void gate_fuse(float* og, const float* __restrict__ xg)
{
    size_t i = ((size_t)blockIdx.x * 256 + threadIdx.x) * 4;
    float4 o = *(float4*)(og + i);
    float4 g = *(const float4*)(xg + i);
    o.x *= 1.0f / (1.0f + expf(-g.x));
    o.y *= 1.0f / (1.0f + expf(-g.y));
    o.z *= 1.0f / (1.0f + expf(-g.z));
    o.w *= 1.0f / (1.0f + expf(-g.w));
    *(float4*)(og + i) = o;
}

// ---------------------------------------------------------------------------
// Per-head RMSNorm in place; one wave per 64-float row.
// ---------------------------------------------------------------------------
__global__ __launch_bounds__(256) void rmsnorm_heads(float* t, const float* __restrict__ w)
{
    int row = blockIdx.x * 4 + (threadIdx.x >> 6);
    int lane = threadIdx.x & 63;
    size_t idx = (size_t)row * 64 + lane;
    float x = t[idx];
    float ss = x * x;
#pragma unroll
    for (int o = 32; o; o >>= 1) ss += __shfl_xor(ss, o);
    float s = rsqrtf(ss * (1.0f / 64.0f) + 1e-6f);
    t[idx] = x * s * w[lane];
}

// ---------------------------------------------------------------------------
// prep: per (inst,d): F = cumprod(sigmoid(fgp)); q*=F; k = exp(igp)*k/F; Fend.
// igp/fgp are fp16 PREACTS (bias already added by GEMM epilogue).
// ---------------------------------------------------------------------------
__global__ __launch_bounds__(256) void prep_kernel(
    float* q, float* k,
    const _Float16* __restrict__ igp, const _Float16* __restrict__ fgp,
    float* __restrict__ Fend)
{
    int gid = blockIdx.x * 256 + threadIdx.x;   // [0, NINST*64)
    int d = gid & 63;
    int inst = gid >> 6;
    int c = inst & (NCC - 1);
    int bh = inst >> 6;
    int b = bh >> 4, h = bh & 15;
    size_t idx = ((size_t)(b * LL + c * TT)) * INNER_ + h * DH + d;
    float F = 1.0f;
    for (int t = 0; t < TT; t++, idx += INNER_) {
        float fgv = 1.0f / (1.0f + expf(-(float)fgp[idx]));
        float igv = expf((float)igp[idx]);
        F *= fgv;
        q[idx] = q[idx] * F;
        k[idx] = igv * k[idx] / F;
    }
    Fend[gid] = F;
}

// ---------------------------------------------------------------------------
// chunk_sum: per inst: G[d][e] = sum_s k~[s][d]*v[s][e]; gsum[d] = sum_s k~[s][d]
// ---------------------------------------------------------------------------
__global__ __launch_bounds__(256) void chunk_sum_kernel(
    const float* __restrict__ kt, const float* __restrict__ v,
    float* __restrict__ G, float* __restrict__ gsum)
{
    __shared__ float ks[TT][68];
    __shared__ float vs[TT][68];
    int inst = blockIdx.x;
    int c = inst & (NCC - 1);
    int bh = inst >> 6;
    int b = bh >> 4, h = bh & 15;
    int tid = threadIdx.x;
    size_t base = ((size_t)(b * LL + c * TT)) * INNER_ + h * DH;
#pragma unroll
    for (int i = 0; i < 4; i++) {
        int id = tid + i * 256;
        int s = id >> 4, dq = (id & 15) * 4;
        *(float4*)&ks[s][dq] = *(const float4*)(kt + base + (size_t)s * INNER_ + dq);
        *(float4*)&vs[s][dq] = *(const float4*)(v + base + (size_t)s * INNER_ + dq);
    }
    __syncthreads();
    int d = tid >> 2;
    int e0 = (tid & 3) * 16;
    float acc[16];
#pragma unroll
    for (int j = 0; j < 16; j++) acc[j] = 0.f;
    float gs = 0.f;
    for (int s = 0; s < TT; s++) {
        float kv = ks[s][d];
        gs += kv;
        const float4* vr = (const float4*)&vs[s][e0];
        float4 v0 = vr[0], v1 = vr[1], v2 = vr[2], v3 = vr[3];
        acc[0] += kv * v0.x; acc[1] += kv * v0.y; acc[2] += kv * v0.z; acc[3] += kv * v0.w;
        acc[4] += kv * v1.x; acc[5] += kv * v1.y; acc[6] += kv * v1.z; acc[7] += kv * v1.w;
        acc[8] += kv * v2.x; acc[9] += kv * v2.y; acc[10] += kv * v2.z; acc[11] += kv * v2.w;
        acc[12] += kv * v3.x; acc[13] += kv * v3.y; acc[14] += kv * v3.z; acc[15] += kv * v3.w;
    }
    float* Gp = G + (size_t)inst * 4096 + (size_t)d * 64 + e0;
#pragma unroll
    for (int j4 = 0; j4 < 4; j4++) {
        float4 o; o.x = acc[j4 * 4]; o.y = acc[j4 * 4 + 1]; o.z = acc[j4 * 4 + 2]; o.w = acc[j4 * 4 + 3];
        *(float4*)&Gp[j4 * 4] = o;
    }
    if ((tid & 3) == 0) gsum[(size_t)inst * 64 + d] = gs;
}

// ---------------------------------------------------------------------------
// state: sequential over chunks; C0[inst]=C; C = Fend_d*(C+G); n likewise.
// ---------------------------------------------------------------------------
__global__ __launch_bounds__(256) void state_kernel(
    const float* __restrict__ G, const float* __restrict__ gsum,
    const float* __restrict__ Fend,
    float* __restrict__ C0, float* __restrict__ n0)
{
    int bh = blockIdx.x >> 4;
    int part = blockIdx.x & 15;
    int p = part * 256 + threadIdx.x;  // [0,4096)
    int d = p >> 6;
    float C = 0.f, n = 0.f;
    for (int c = 0; c < NCC; c++) {
        size_t inst = (size_t)bh * NCC + c;
        C0[inst * 4096 + p] = C;
        float f = Fend[inst * 64 + d];
        C = f * (C + G[inst * 4096 + p]);
        if (p < 64) {
            n0[inst * 64 + p] = n;
            n = Fend[inst * 64 + p] * (n + gsum[inst * 64 + p]);
        }
    }
}

// ---------------------------------------------------------------------------
// scan_out: A=tril(q~k~^T); den=max(q~.n0+rowsum(A),1);
// num = q~@C0 + A@V; g = fp16(num/den * og')   (og' includes sigmoid(x_gate))
// ---------------------------------------------------------------------------
__global__ __launch_bounds__(256) void scan_out_kernel(
    const float* __restrict__ qt, const float* __restrict__ kt,
    const float* __restrict__ v, const float* __restrict__ og,
    const float* __restrict__ C0, const float* __restrict__ n0,
    _Float16* __restrict__ g)
{
    __shared__ float Qs[TT][68];
    __shared__ float Ks[TT][68];
    __shared__ float As[TT][68];
    __shared__ float den[TT];
    int inst = blockIdx.x;
    int c = inst & (NCC - 1);
    int bh = inst >> 6;
    int b = bh >> 4, h = bh & 15;
    int tid = threadIdx.x;
    size_t base = ((size_t)(b * LL + c * TT)) * INNER_ + h * DH;

#pragma unroll
    for (int i = 0; i < 4; i++) {
        int id = tid + i * 256;
        int s = id >> 4, dq = (id & 15) * 4;
        *(float4*)&Qs[s][dq] = *(const float4*)(qt + base + (size_t)s * INNER_ + dq);
        *(float4*)&Ks[s][dq] = *(const float4*)(kt + base + (size_t)s * INNER_ + dq);
    }
    __syncthreads();

    const int trow = tid >> 2;
    const int s0 = tid & 3;
    {
        float a[16];
#pragma unroll
        for (int j = 0; j < 16; j++) a[j] = 0.f;
        for (int d4 = 0; d4 < 16; d4++) {
            float4 qv = *(const float4*)&Qs[trow][d4 * 4];
#pragma unroll
            for (int j = 0; j < 16; j++) {
                float4 kv = *(const float4*)&Ks[s0 + 4 * j][d4 * 4];
                a[j] += qv.x * kv.x + qv.y * kv.y + qv.z * kv.z + qv.w * kv.w;
            }
        }
#pragma unroll
        for (int j = 0; j < 16; j++) {
            int s = s0 + 4 * j;
            As[trow][s] = (s <= trow) ? a[j] : 0.f;
        }
    }
    __syncthreads();

#pragma unroll
    for (int i = 0; i < 4; i++) {
        int id = tid + i * 256;
        int d = id >> 4, eq = (id & 15) * 4;
        *(float4*)&Ks[d][eq] = *(const float4*)(C0 + (size_t)inst * 4096 + (size_t)d * 64 + eq);
    }
    if (tid < TT) {
        float s = 0.f;
#pragma unroll 8
        for (int j = 0; j < TT; j++) s += As[tid][j];
        const float* n0p = n0 + (size_t)inst * 64;
        float dn = 0.f;
#pragma unroll 8
        for (int d = 0; d < DH; d++) dn += Qs[tid][d] * n0p[d];
        den[tid] = fmaxf(s + dn, 1.0f);
    }
    __syncthreads();

    const int e0 = (tid & 3) * 16;
    float num[16];
#pragma unroll
    for (int j = 0; j < 16; j++) num[j] = 0.f;

    for (int d = 0; d < DH; d++) {
        float qd = Qs[trow][d];
        const float4* kr = (const float4*)&Ks[d][e0];
        float4 k0 = kr[0], k1 = kr[1], k2 = kr[2], k3 = kr[3];
        num[0] += qd * k0.x; num[1] += qd * k0.y; num[2] += qd * k0.z; num[3] += qd * k0.w;
        num[4] += qd * k1.x; num[5] += qd * k1.y; num[6] += qd * k1.z; num[7] += qd * k1.w;
        num[8] += qd * k2.x; num[9] += qd * k2.y; num[10] += qd * k2.z; num[11] += qd * k2.w;
        num[12] += qd * k3.x; num[13] += qd * k3.y; num[14] += qd * k3.z; num[15] += qd * k3.w;
    }
    __syncthreads();

#pragma unroll
    for (int i = 0; i < 4; i++) {
        int id = tid + i * 256;
        int s = id >> 4, dq = (id & 15) * 4;
        *(float4*)&Qs[s][dq] = *(const float4*)(v + base + (size_t)s * INNER_ + dq);
    }
    __syncthreads();

    for (int s = 0; s < TT; s++) {
        float av = As[trow][s];
        const float4* vr = (const float4*)&Qs[s][e0];
        float4 v0 = vr[0], v1 = vr[1], v2 = vr[2], v3 = vr[3];
        num[0] += av * v0.x; num[1] += av * v0.y; num[2] += av * v0.z; num[3] += av * v0.w;
        num[4] += av * v1.x; num[5] += av * v1.y; num[6] += av * v1.z; num[7] += av * v1.w;
        num[8] += av * v2.x; num[9] += av * v2.y; num[10] += av * v2.z; num[11] += av * v2.w;
        num[12] += av * v3.x; num[13] += av * v3.y; num[14] += av * v3.z; num[15] += av * v3.w;
    }

    float inv = 1.0f / den[trow];
    size_t orow = base + (size_t)trow * INNER_ + e0;
#pragma unroll
    for (int j = 0; j < 16; j++) {
        g[orow + j] = (_Float16)(num[j] * inv * og[orow + j]);
    }
}

// diagnostic: encode ws_size (MB) into out[0] if workspace too small
__global__ void ws_sentinel(float* out, float v) { out[0] = v; }

// ---------------------------------------------------------------------------
extern "C" void kernel_launch(void* const* d_in, const int* in_sizes, int n_in,
                              void* d_out, int out_size, void* d_ws, size_t ws_size,
                              hipStream_t stream)
{
    const float* x          = (const float*)d_in[0];
    const float* in_proj_w  = (const float*)d_in[1];
    const float* q_proj_w   = (const float*)d_in[2];
    const float* k_proj_w   = (const float*)d_in[3];
    const float* v_proj_w   = (const float*)d_in[4];
    const float* i_gate_w   = (const float*)d_in[5];
    const float* i_gate_b   = (const float*)d_in[6];
    const float* f_gate_w   = (const float*)d_in[7];
    const float* f_gate_b   = (const float*)d_in[8];
    const float* o_gate_w   = (const float*)d_in[9];
    const float* o_gate_b   = (const float*)d_in[10];
    const float* q_norm_w   = (const float*)d_in[11];
    const float* k_norm_w   = (const float*)d_in[12];
    const float* out_proj_w = (const float*)d_in[13];
    float* out = (float*)d_out;

    const size_t MB1 = (size_t)1 << 20;
    const size_t NEED = 179 * MB1 + 512 * 1024;   // 179.5 MB
    if (ws_size < NEED) {
        ws_sentinel<<<1, 1, 0, stream>>>(out, 1000.0f + (float)(ws_size >> 20));
        return;
    }
    char* ws = (char*)d_ws;
    _Float16* xh  = (_Float16*)(ws + 0 * MB1);    // 16MB
    _Float16* xih = (_Float16*)(ws + 16 * MB1);   // 16MB
    _Float16* igp = (_Float16*)(ws + 32 * MB1);   // 16MB
    _Float16* fgp = (_Float16*)(ws + 48 * MB1);   // 16MB
    float* xg = (float*)(ws + 64 * MB1);          // 32MB; later v
    float* qb = (float*)(ws + 96 * MB1);          // 32MB
    float* kb = (float*)(ws + 128 * MB1);         // 32MB
    _Float16* wh = (_Float16*)(ws + 160 * MB1);   // 18MB weights
    float* Fend = (float*)(ws + 178 * MB1);
    float* gsum = (float*)(ws + 178 * MB1 + 512 * 1024);
    float* n0   = (float*)(ws + 179 * MB1);
    // overlays (live ranges verified):
    float* C0 = (float*)(ws + 0 * MB1);                 // after xh/xih dead
    float* G  = (float*)(ws + 32 * MB1);                // after igp/fgp dead
    _Float16* gh = (_Float16*)(ws + 32 * MB1);          // after G dead
    float* vb = xg;                                     // after gate_fuse
    float* ogb = out;                                   // og in d_out until final GEMM

    _Float16* w_inproj = wh;                      // 2048x1024
    _Float16* w_q   = wh + 2048 * 1024;
    _Float16* w_k   = w_q + 1024 * 1024;
    _Float16* w_v   = w_k + 1024 * 1024;
    _Float16* w_i   = w_v + 1024 * 1024;
    _Float16* w_f   = w_i + 1024 * 1024;
    _Float16* w_o   = w_f + 1024 * 1024;
    _Float16* w_out = w_o + 1024 * 1024;

    dim3 blk(256);
    dim3 gg(1024 / MBN, MTOK / MBM);   // (8, 64)

    // casts
    cast_f2h<<<8192, blk, 0, stream>>>(x, xh, 2097152);
    cast_f2h<<<2048, blk, 0, stream>>>(in_proj_w, w_inproj, 524288);
    cast_f2h<<<1024, blk, 0, stream>>>(q_proj_w, w_q, 262144);
    cast_f2h<<<1024, blk, 0, stream>>>(k_proj_w, w_k, 262144);
    cast_f2h<<<1024, blk, 0, stream>>>(v_proj_w, w_v, 262144);
    cast_f2h<<<1024, blk, 0, stream>>>(i_gate_w, w_i, 262144);
    cast_f2h<<<1024, blk, 0, stream>>>(f_gate_w, w_f, 262144);
    cast_f2h<<<1024, blk, 0, stream>>>(o_gate_w, w_o, 262144);
    cast_f2h<<<1024, blk, 0, stream>>>(out_proj_w, w_out, 262144);

    // projections
    gemm_f16<<<gg, blk, 0, stream>>>(xh, 1024, w_inproj, 1024, xih, 1024, 1024, nullptr, 0, 1);
    gemm_f16<<<gg, blk, 0, stream>>>(xh, 1024, w_inproj + 1024 * 1024, 1024, xg, 1024, 1024, nullptr, 0, 0);
    gemm_f16<<<gg, blk, 0, stream>>>(xih, 1024, w_o, 1024, ogb, 1024, 1024, o_gate_b, 2, 0);
    gate_fuse<<<MTOK * 1024 / (256 * 4), blk, 0, stream>>>(ogb, xg);   // frees xg
    gemm_f16<<<gg, blk, 0, stream>>>(xih, 1024, w_q, 1024, qb, 1024, 1024, nullptr, 0, 0);
    gemm_f16<<<gg, blk, 0, stream>>>(xih, 1024, w_k, 1024, kb, 1024, 1024, nullptr, 0, 0);
    gemm_f16<<<gg, blk, 0, stream>>>(xih, 1024, w_v, 1024, vb, 1024, 1024, nullptr, 0, 0);
    gemm_f16<<<gg, blk, 0, stream>>>(xih, 1024, w_i, 1024, igp, 1024, 1024, i_gate_b, 1, 1);
    gemm_f16<<<gg, blk, 0, stream>>>(xih, 1024, w_f, 1024, fgp, 1024, 1024, f_gate_b, 1, 1);

    // scan (fp32)
    rmsnorm_heads<<<MTOK * NH / 4, blk, 0, stream>>>(qb, q_norm_w);
    rmsnorm_heads<<<MTOK * NH / 4, blk, 0, stream>>>(kb, k_norm_w);
    prep_kernel<<<NINST * 64 / 256, blk, 0, stream>>>(qb, kb, igp, fgp, Fend);
    chunk_sum_kernel<<<NINST, blk, 0, stream>>>(kb, vb, G, gsum);
    state_kernel<<<32 * 16, blk, 0, stream>>>(G, gsum, Fend, C0, n0);
    scan_out_kernel<<<NINST, blk, 0, stream>>>(qb, kb, vb, ogb, C0, n0, gh);

    // out = g @ out_proj^T
    gemm_f16<<<gg, blk, 0, stream>>>(gh, 1024, w_out, 1024, out, 1024, 1024, nullptr, 0, 0);
}